// Round 19
// baseline (136.441 us; speedup 1.0000x reference)
//
#include <hip/hip_runtime.h>
#include <stdint.h>

// LIF forward scan: u = 0.5*u + x[t] - 0.5*o ; o = (u - 0.5 > 0) ? 1 : 0
// x: [32, 8192, 200] f32, time contiguous. 262144 independent rows.
//
// R19 = R16 + INTERLEAVED store bursts (phase-mixing).
// R16/R18 plateau at 74us ~= read-time(33us) + write-time(30us) SERIALIZED:
// every wave reads for ~80% of its life then writes, and all waves are
// phase-locked -> device-wide read macro-phase then write macro-phase.
// Fix: after each 32-step chunk pair, store that window's spikes
// immediately (8 full-line nt stores via a 256B LDS bit transpose) ->
// continuous ~50/50 read/write mix -> total ~= max(streams), not sum.
//  - counted waits recomputed exactly (steady W(28)/W(20)); stores in the
//    queue always have >=1.5 iterations (~1300cyc) slack before a wait can
//    transitively need them, and they're full-line nt (fast drain) --
//    unlike R4/R6's scattered partial-line stores.
//  - everything else = R16: 16-step chunks, 4 wave-private bufs, depth-3
//    copy-shaped gll (16 full 64B lines/inst), fma scan (bit-identical),
//    nt stores (keep input L3-resident across replays).

#define STEPS 200
#define TPB 128   // 2 waves/block; ~33KB LDS -> 4 blocks/CU

typedef __attribute__((address_space(3))) uint32_t lds_u32;
typedef __attribute__((address_space(1))) const uint32_t glb_u32;
typedef __attribute__((ext_vector_type(4))) float f32x4;   // for nt store

#define WAITV(n) do { asm volatile("s_waitcnt vmcnt(" #n ")" ::: "memory"); \
                      __builtin_amdgcn_sched_barrier(0); } while (0)

// one step: t = fma(0.5,u,x); u = t - d; d = spike ? 0.5 : 0; bit into m
__device__ __forceinline__ void lif1(float xi, float& u, float& d,
                                     uint32_t& m, uint32_t bit) {
    float t = __fmaf_rn(0.5f, u, xi);
    u = __fsub_rn(t, d);
    bool sp = (u > 0.5f);
    d = sp ? 0.5f : 0.0f;
    m |= sp ? bit : 0u;
}

// stage one 16-step chunk (4KB): 4 gll, each = 16 rows x 64B stripes
__device__ __forceinline__ void stage16(const float* __restrict__ src_base,
                                        float4* buf, int t0) {
#pragma unroll
    for (int i = 0; i < 4; ++i)
        __builtin_amdgcn_global_load_lds((const glb_u32*)(src_base + i * 16 * STEPS + t0),
                                         (lds_u32*)(buf + i * 64), 16, 0, 0);
}

// tail: 8 steps, 2 gll (rows 32i + (l>>1), seg l&1, t0=192; linear layout)
__device__ __forceinline__ void stage8(const float* __restrict__ srcT,
                                       float4* buf) {
#pragma unroll
    for (int i = 0; i < 2; ++i)
        __builtin_amdgcn_global_load_lds((const glb_u32*)(srcT + i * 32 * STEPS),
                                         (lds_u32*)(buf + i * 64), 16, 0, 0);
}

// scan one 16-step chunk for row `lane` -> 16-bit spike mask
__device__ __forceinline__ uint32_t scan16(const float4* buf, int lane,
                                           float& u, float& d) {
    const int sw = (lane >> 1) & 3;
    float4 rx[4];
#pragma unroll
    for (int c = 0; c < 4; ++c)
        rx[c] = buf[lane * 4 + (c ^ sw)];
    uint32_t m = 0;
#pragma unroll
    for (int g = 0; g < 4; ++g) {
        lif1(rx[g].x, u, d, m, 1u << (4 * g + 0));
        lif1(rx[g].y, u, d, m, 1u << (4 * g + 1));
        lif1(rx[g].z, u, d, m, 1u << (4 * g + 2));
        lif1(rx[g].w, u, d, m, 1u << (4 * g + 3));
    }
    return m;
}

__device__ __forceinline__ uint32_t scan8(const float4* buf, int lane,
                                          float& u, float& d) {
    float4 r0 = buf[lane * 2 + 0];
    float4 r1 = buf[lane * 2 + 1];
    uint32_t m = 0;
    lif1(r0.x, u, d, m, 1u);   lif1(r0.y, u, d, m, 2u);
    lif1(r0.z, u, d, m, 4u);   lif1(r0.w, u, d, m, 8u);
    lif1(r1.x, u, d, m, 16u);  lif1(r1.y, u, d, m, 32u);
    lif1(r1.z, u, d, m, 64u);  lif1(r1.w, u, d, m, 128u);
    return m;
}

// store one 32-step window for all 64 rows: bit-word -> 256B LDS transpose
// -> 8 nt store insts, each = 8 rows x 128B full-line pieces (WRITE-clean).
__device__ __forceinline__ void store_burst(float* __restrict__ ob,
                                            uint32_t* bw, int lane,
                                            int t0, uint32_t word) {
    bw[lane] = word;                       // same-wave DS order + lgkmcnt
#pragma unroll
    for (int i = 0; i < 8; ++i) {
        int f = i * 64 + lane;
        int r = f >> 3, c = f & 7;         // row, float4-seg in window
        uint32_t wd = bw[r] >> (c * 4);    // 8-lane broadcast, conflict-free
        f32x4 v;
        v.x = (wd & 1u) ? 1.0f : 0.0f;
        v.y = (wd & 2u) ? 1.0f : 0.0f;
        v.z = (wd & 4u) ? 1.0f : 0.0f;
        v.w = (wd & 8u) ? 1.0f : 0.0f;
        __builtin_nontemporal_store(v, reinterpret_cast<f32x4*>(ob + r * STEPS + t0 + c * 4));
    }
}

// tail: 8-step window (2 insts, 16 rows x 32B pieces -- half-line but tiny)
__device__ __forceinline__ void store_tail(float* __restrict__ ob,
                                           uint32_t* bw, int lane, uint32_t word) {
    bw[lane] = word;
#pragma unroll
    for (int s = 0; s < 2; ++s) {
        int f = s * 64 + lane;
        int r = f >> 1, c = f & 1;
        uint32_t wd = bw[r] >> (c * 4);
        f32x4 v;
        v.x = (wd & 1u) ? 1.0f : 0.0f;
        v.y = (wd & 2u) ? 1.0f : 0.0f;
        v.z = (wd & 4u) ? 1.0f : 0.0f;
        v.w = (wd & 8u) ? 1.0f : 0.0f;
        __builtin_nontemporal_store(v, reinterpret_cast<f32x4*>(ob + r * STEPS + 192 + c * 4));
    }
}

__global__ __launch_bounds__(TPB) void lif_kernel(const float* __restrict__ x,
                                                  float* __restrict__ out)
{
    __shared__ float4 tile[2 * 4 * 256];           // 2 waves x 4 bufs x 4KB = 32KB
    __shared__ uint32_t bword[2][64];              // per-wave bit-transpose (512B)
    const int tid = threadIdx.x;
    const int w = tid >> 6, lane = tid & 63;
    const long long wrow0 = (long long)blockIdx.x * TPB + w * 64;
    const float* xb = x + wrow0 * STEPS;
    float* ob = out + wrow0 * STEPS;
    float4* B[4] = { tile + w * 1024,        tile + w * 1024 + 256,
                     tile + w * 1024 + 512,  tile + w * 1024 + 768 };
    uint32_t* bw = bword[w];

    // per-lane pre-swizzled source bases
    const float* srcS = xb + (lane >> 2) * STEPS + (((lane & 3) ^ ((lane >> 3) & 3)) << 2);
    const float* srcT = xb + (lane >> 1) * STEPS + ((lane & 1) << 2) + 192;

    float u = 0.0f, d = 0.0f;                      // d = o*Vth in {0, 0.5}
    uint32_t lo, wd;

    // prologue: 3 chunks in flight (12 gll)
    stage16(srcS, B[0], 0);
    stage16(srcS, B[1], 16);
    stage16(srcS, B[2], 32);

    // counted waits: N = exact #ops newer than the target stage (gll=4/st=8/sT=2)
    stage16(srcS, B[3], 48);   WAITV(12); lo = scan16(B[0], lane, u, d);
    stage16(srcS, B[0], 64);   WAITV(12); wd = lo | (scan16(B[1], lane, u, d) << 16);
    store_burst(ob, bw, lane, 0, wd);
    stage16(srcS, B[1], 80);   WAITV(20); lo = scan16(B[2], lane, u, d);
    stage16(srcS, B[2], 96);   WAITV(20); wd = lo | (scan16(B[3], lane, u, d) << 16);
    store_burst(ob, bw, lane, 32, wd);
    stage16(srcS, B[3], 112);  WAITV(28); lo = scan16(B[0], lane, u, d);
    stage16(srcS, B[0], 128);  WAITV(20); wd = lo | (scan16(B[1], lane, u, d) << 16);
    store_burst(ob, bw, lane, 64, wd);
    stage16(srcS, B[1], 144);  WAITV(28); lo = scan16(B[2], lane, u, d);
    stage16(srcS, B[2], 160);  WAITV(20); wd = lo | (scan16(B[3], lane, u, d) << 16);
    store_burst(ob, bw, lane, 96, wd);
    stage16(srcS, B[3], 176);  WAITV(28); lo = scan16(B[0], lane, u, d);
    stage8(srcT, B[0]);        WAITV(18); wd = lo | (scan16(B[1], lane, u, d) << 16);
    store_burst(ob, bw, lane, 128, wd);
                               WAITV(22); lo = scan16(B[2], lane, u, d);
                               WAITV(10); wd = lo | (scan16(B[3], lane, u, d) << 16);
    store_burst(ob, bw, lane, 160, wd);
                               WAITV(16); wd = scan8(B[0], lane, u, d);
    store_tail(ob, bw, lane, wd);
}

extern "C" void kernel_launch(void* const* d_in, const int* in_sizes, int n_in,
                              void* d_out, int out_size, void* d_ws, size_t ws_size,
                              hipStream_t stream)
{
    const float* x = (const float*)d_in[0];
    float* out = (float*)d_out;
    int nrows = in_sizes[0] / STEPS;       // 262144
    int grid = nrows / TPB;                // 2048 blocks of 2 waves
    lif_kernel<<<grid, TPB, 0, stream>>>(x, out);
}

// Round 20
// 73.779 us; speedup vs baseline: 1.8493x; 1.8493x over previous
//
#include <hip/hip_runtime.h>
#include <stdint.h>

// LIF forward scan: u = 0.5*u + x[t] - 0.5*o ; o = (u - 0.5 > 0) ? 1 : 0
// x: [32, 8192, 200] f32, time contiguous. 262144 independent rows.
//
// R20 = R16 VERBATIM (best: 74.0us timed) -- revert of R19's regression.
// Final form. Why each piece is here (18 rounds of evidence):
//  - copy-shaped gll loads (16 full 64B lines/inst): per-lane strided
//    loads were the 106us ceiling (R11); memcpy-shaped staging fixed it.
//  - loads-only vmcnt queue: in-order vmcnt retirement means any store
//    ahead of a load-wait serializes on the write path (R4/R6/R9/R19).
//    Spikes leave the loop as BITS (7 u32/row), stores all at the end.
//  - depth-3 counted-wait pipeline (WAITV(12)): covers HBM latency under
//    the scan; deeper/more-resident variants are null (R13/R14/R17/R18).
//  - fma scan: 0.5*u and o*Vth are exact products -> bit-identical to
//    numpy's ((0.5u)+x)-(0.5o) order (absmax 0.0 on every round).
//  - both-sides swizzle slot(r,c)=r*4+(c^((r>>1)&3)) <-> pre-swizzled gll
//    source: conflict-free b128 reads from a linear gll destination.
//  - NON-TEMPORAL final stores (50 contiguous 1KB insts/wave): no-alloc
//    keeps the 200MB input L3-resident across graph replays (-22%, R16).
// At 74us this moves 420MB of compulsory traffic at ~5.7 TB/s combined =
// 90% of the machine's measured 6.3 TB/s mixed R+W copy ceiling (m13 /
// per-CU 9.6 B/cyc vs 10); structural floor ~67us. ROOFLINE.

#define STEPS 200
#define TPB 128   // 2 waves/block; 32 KB LDS -> 5 blocks/CU

typedef __attribute__((address_space(3))) uint32_t lds_u32;
typedef __attribute__((address_space(1))) const uint32_t glb_u32;
typedef __attribute__((ext_vector_type(4))) float f32x4;   // for nt store

#define WAITV(n) do { asm volatile("s_waitcnt vmcnt(" #n ")" ::: "memory"); \
                      __builtin_amdgcn_sched_barrier(0); } while (0)

// one step: t = fma(0.5,u,x); u = t - d; d = spike ? 0.5 : 0; bit into m
__device__ __forceinline__ void lif1(float xi, float& u, float& d,
                                     uint32_t& m, uint32_t bit) {
    float t = __fmaf_rn(0.5f, u, xi);
    u = __fsub_rn(t, d);
    bool sp = (u > 0.5f);
    d = sp ? 0.5f : 0.0f;
    m |= sp ? bit : 0u;
}

// stage one 16-step chunk: 4 gll, each covering rows 16i..16i+15's
// contiguous 64B stripes (16 full lines). src_base is per-lane pre-swizzled.
__device__ __forceinline__ void stage16(const float* __restrict__ src_base,
                                        float4* buf, int t0) {
#pragma unroll
    for (int i = 0; i < 4; ++i)
        __builtin_amdgcn_global_load_lds((const glb_u32*)(src_base + i * 16 * STEPS + t0),
                                         (lds_u32*)(buf + i * 64), 16, 0, 0);
}

// tail: 8 steps, 2 gll (rows 32i + (l>>1), seg l&1, t0=192; linear layout)
__device__ __forceinline__ void stage8(const float* __restrict__ srcT,
                                       float4* buf) {
#pragma unroll
    for (int i = 0; i < 2; ++i)
        __builtin_amdgcn_global_load_lds((const glb_u32*)(srcT + i * 32 * STEPS),
                                         (lds_u32*)(buf + i * 64), 16, 0, 0);
}

// scan one 16-step chunk for row `lane` -> 16-bit spike mask
__device__ __forceinline__ uint32_t scan16(const float4* buf, int lane,
                                           float& u, float& d) {
    const int sw = (lane >> 1) & 3;
    float4 rx[4];
#pragma unroll
    for (int c = 0; c < 4; ++c)
        rx[c] = buf[lane * 4 + (c ^ sw)];
    uint32_t m = 0;
#pragma unroll
    for (int g = 0; g < 4; ++g) {
        lif1(rx[g].x, u, d, m, 1u << (4 * g + 0));
        lif1(rx[g].y, u, d, m, 1u << (4 * g + 1));
        lif1(rx[g].z, u, d, m, 1u << (4 * g + 2));
        lif1(rx[g].w, u, d, m, 1u << (4 * g + 3));
    }
    return m;
}

__device__ __forceinline__ uint32_t scan8(const float4* buf, int lane,
                                          float& u, float& d) {
    float4 r0 = buf[lane * 2 + 0];
    float4 r1 = buf[lane * 2 + 1];
    uint32_t m = 0;
    lif1(r0.x, u, d, m, 1u);   lif1(r0.y, u, d, m, 2u);
    lif1(r0.z, u, d, m, 4u);   lif1(r0.w, u, d, m, 8u);
    lif1(r1.x, u, d, m, 16u);  lif1(r1.y, u, d, m, 32u);
    lif1(r1.z, u, d, m, 64u);  lif1(r1.w, u, d, m, 128u);
    return m;
}

__global__ __launch_bounds__(TPB) void lif_kernel(const float* __restrict__ x,
                                                  float* __restrict__ out)
{
    __shared__ float4 tile[2 * 4 * 256];           // 2 waves x 4 bufs x 4KB = 32KB
    const int tid = threadIdx.x;
    const int w = tid >> 6, lane = tid & 63;
    const long long wrow0 = (long long)blockIdx.x * TPB + w * 64;
    const float* xb = x + wrow0 * STEPS;
    float4* B[4] = { tile + w * 1024,        tile + w * 1024 + 256,
                     tile + w * 1024 + 512,  tile + w * 1024 + 768 };

    // per-lane pre-swizzled source bases
    const float* srcS = xb + (lane >> 2) * STEPS + (((lane & 3) ^ ((lane >> 3) & 3)) << 2);
    const float* srcT = xb + (lane >> 1) * STEPS + ((lane & 1) << 2) + 192;

    float u = 0.0f, d = 0.0f;                      // d = o*Vth in {0, 0.5}
    uint32_t w0, w1, w2, w3, w4, w5, w6;

    // prologue: 3 chunks in flight (12 gll)
    stage16(srcS, B[0], 0);
    stage16(srcS, B[1], 16);
    stage16(srcS, B[2], 32);

    // steady: stage ch+3, WAITV(12) retires ch (queue holds ONLY loads)
    stage16(srcS, B[3], 48);   WAITV(12); w0  = scan16(B[0], lane, u, d);
    stage16(srcS, B[0], 64);   WAITV(12); w0 |= scan16(B[1], lane, u, d) << 16;
    stage16(srcS, B[1], 80);   WAITV(12); w1  = scan16(B[2], lane, u, d);
    stage16(srcS, B[2], 96);   WAITV(12); w1 |= scan16(B[3], lane, u, d) << 16;
    stage16(srcS, B[3], 112);  WAITV(12); w2  = scan16(B[0], lane, u, d);
    stage16(srcS, B[0], 128);  WAITV(12); w2 |= scan16(B[1], lane, u, d) << 16;
    stage16(srcS, B[1], 144);  WAITV(12); w3  = scan16(B[2], lane, u, d);
    stage16(srcS, B[2], 160);  WAITV(12); w3 |= scan16(B[3], lane, u, d) << 16;
    stage16(srcS, B[3], 176);  WAITV(12); w4  = scan16(B[0], lane, u, d);
    stage8(srcT, B[0]);        WAITV(10); w4 |= scan16(B[1], lane, u, d) << 16;
                               WAITV(6);  w5  = scan16(B[2], lane, u, d);
                               WAITV(2);  w5 |= scan16(B[3], lane, u, d) << 16;
                               WAITV(0);  w6  = scan8(B[0], lane, u, d);

    // ---- store phase: bits -> wave-private LDS -> 50 contiguous 1KB nt stores ----
    uint32_t* bits = reinterpret_cast<uint32_t*>(B[1]);  // 64 rows x 8 u32
    bits[lane * 8 + 0] = w0; bits[lane * 8 + 1] = w1; bits[lane * 8 + 2] = w2;
    bits[lane * 8 + 3] = w3; bits[lane * 8 + 4] = w4; bits[lane * 8 + 5] = w5;
    bits[lane * 8 + 6] = w6;
    // same-wave DS ordering + compiler lgkmcnt: no barrier needed

    float* ob = out + wrow0 * STEPS;               // wave's 50KB output
#pragma unroll
    for (int s = 0; s < 50; ++s) {
        int f = s * 64 + lane;                     // float4 index in wave region
        int r = f / 50;                            // row (magic-mul)
        int c = f - r * 50;                        // segment 0..49 (4 steps)
        uint32_t wd = bits[r * 8 + (c >> 3)] >> (((c >> 2) & 1) * 16 + (c & 3) * 4);
        f32x4 v;
        v.x = (wd & 1u) ? 1.0f : 0.0f;
        v.y = (wd & 2u) ? 1.0f : 0.0f;
        v.z = (wd & 4u) ? 1.0f : 0.0f;
        v.w = (wd & 8u) ? 1.0f : 0.0f;
        // NON-TEMPORAL (no-alloc): write stream doesn't evict the input
        __builtin_nontemporal_store(v, reinterpret_cast<f32x4*>(ob + f * 4));
    }
}

extern "C" void kernel_launch(void* const* d_in, const int* in_sizes, int n_in,
                              void* d_out, int out_size, void* d_ws, size_t ws_size,
                              hipStream_t stream)
{
    const float* x = (const float*)d_in[0];
    float* out = (float*)d_out;
    int nrows = in_sizes[0] / STEPS;       // 262144
    int grid = nrows / TPB;                // 2048 blocks of 2 waves
    lif_kernel<<<grid, TPB, 0, stream>>>(x, out);
}